// Round 6
// baseline (284.140 us; speedup 1.0000x reference)
//
#include <hip/hip_runtime.h>
#include <math.h>

// Problem constants
constexpr int Bc = 8;
constexpr int Lc = 1024;
constexpr int Dc = 512;        // model dim
constexpr int Hc = 8;
constexpr int DHc = 64;
constexpr int DLc = 64;
constexpr int NBc = 128;
constexpr int TOTAL_OUT = 2 * DLc * Hc + 2 * DHc * Hc;  // 2048
constexpr int ROWS = Bc * Lc;  // 8192

using f32x4 = __attribute__((ext_vector_type(4))) float;
using s16x8 = __attribute__((ext_vector_type(8))) short;

__device__ __forceinline__ float bf2f(ushort u) {
    union { unsigned int i; float f; } v; v.i = ((unsigned int)u) << 16; return v.f;
}
__device__ __forceinline__ ushort f2bf(float f) {
    union { float f; unsigned int i; } v; v.f = f;
    unsigned int r = v.i + 0x7fffu + ((v.i >> 16) & 1u);  // RNE
    return (ushort)(r >> 16);
}
// silu via v_exp + v_rcp (1-instr transcendentals) instead of precise divide
__device__ __forceinline__ float silu(float x) {
    float e = __expf(-x);
    return x * __builtin_amdgcn_rcpf(1.0f + e);
}

// ---------------------------------------------------------------------------
// Transpose + cast fp32 (R x C) -> bf16 (C x R)
// ---------------------------------------------------------------------------
__global__ __launch_bounds__(256) void transpose_cast(const float* __restrict__ in,
                                                      ushort* __restrict__ out,
                                                      int R, int C) {
    __shared__ float tile[32][33];
    int bc = blockIdx.x * 32, br = blockIdx.y * 32;
    int tx = threadIdx.x & 31, ty = threadIdx.x >> 5;  // 32x8
    for (int i = ty; i < 32; i += 8) {
        int r = br + i, c = bc + tx;
        tile[i][tx] = (r < R && c < C) ? in[(size_t)r * C + c] : 0.f;
    }
    __syncthreads();
    for (int i = ty; i < 32; i += 8) {
        int c = bc + i, r = br + tx;
        if (c < C && r < R) out[(size_t)c * R + r] = f2bf(tile[tx][i]);
    }
}

// ---------------------------------------------------------------------------
// LN1: x (ROWS x 512 fp32) -> bf16 normalized. One wave per row.
// ---------------------------------------------------------------------------
__global__ __launch_bounds__(256) void ln1_kernel(const float* __restrict__ x,
                                                  const float* __restrict__ g,
                                                  const float* __restrict__ bta,
                                                  ushort* __restrict__ outp) {
    int wid = threadIdx.x >> 6, lane = threadIdx.x & 63;
    int row = blockIdx.x * 4 + wid;
    const float4* xr = (const float4*)(x + (size_t)row * Dc);
    float4 a = xr[lane * 2], c = xr[lane * 2 + 1];
    float xv[8] = {a.x, a.y, a.z, a.w, c.x, c.y, c.z, c.w};
    float s = 0.f, q = 0.f;
#pragma unroll
    for (int i = 0; i < 8; i++) { s += xv[i]; q += xv[i] * xv[i]; }
#pragma unroll
    for (int off = 32; off; off >>= 1) { s += __shfl_xor(s, off); q += __shfl_xor(q, off); }
    float mean = s * (1.f / 512.f);
    float var  = q * (1.f / 512.f) - mean * mean;
    float rstd = rsqrtf(var + 1e-6f);
    const float4* gv = (const float4*)g; const float4* bv = (const float4*)bta;
    float4 g0 = gv[lane * 2], g1 = gv[lane * 2 + 1];
    float4 b0 = bv[lane * 2], b1 = bv[lane * 2 + 1];
    float G[8] = {g0.x, g0.y, g0.z, g0.w, g1.x, g1.y, g1.z, g1.w};
    float Bv[8] = {b0.x, b0.y, b0.z, b0.w, b1.x, b1.y, b1.z, b1.w};
    union { ushort u16[8]; uint4 v; } pk;
#pragma unroll
    for (int i = 0; i < 8; i++) pk.u16[i] = f2bf((xv[i] - mean) * rstd * G[i] + Bv[i]);
    ((uint4*)(outp + (size_t)row * Dc))[lane] = pk.v;
}

// ---------------------------------------------------------------------------
// GEMM1: X1 (8192x512 bf16) @ W1T^T -> silu -> split-store:
//   u, q, k row-major (8192x512 each); V TRANSPOSED: VT[(b*8+h)*64+d][n] (64 heads)
// ---------------------------------------------------------------------------
__global__ __launch_bounds__(256) void gemm1_kernel(const ushort* __restrict__ A,
                                                    const ushort* __restrict__ Bt,
                                                    ushort* __restrict__ Ub,
                                                    ushort* __restrict__ VTg,
                                                    ushort* __restrict__ Qb,
                                                    ushort* __restrict__ Kb) {
    __shared__ __align__(16) ushort As[128][72];
    __shared__ __align__(16) ushort Bs[128][72];
    int tid = threadIdx.x;
    int m0 = blockIdx.x * 128, n0 = blockIdx.y * 128;
    int w = tid >> 6, lane = tid & 63;
    int wm = (w >> 1) * 64, wn = (w & 1) * 64;
    f32x4 acc[4][4] = {};
    for (int k0 = 0; k0 < Dc; k0 += 64) {
        __syncthreads();
#pragma unroll
        for (int c = tid; c < 1024; c += 256) {
            int r = c >> 3, c8 = c & 7;
            *(uint4*)&As[r][c8 * 8] = *(const uint4*)&A[(size_t)(m0 + r) * Dc + k0 + c8 * 8];
            *(uint4*)&Bs[r][c8 * 8] = *(const uint4*)&Bt[(size_t)(n0 + r) * Dc + k0 + c8 * 8];
        }
        __syncthreads();
#pragma unroll
        for (int ks = 0; ks < 2; ++ks) {
            int kb = ks * 32 + (lane >> 4) * 8;
            s16x8 af[4], bfr[4];
#pragma unroll
            for (int i = 0; i < 4; i++) af[i] = *(const s16x8*)&As[wm + i * 16 + (lane & 15)][kb];
#pragma unroll
            for (int j = 0; j < 4; j++) bfr[j] = *(const s16x8*)&Bs[wn + j * 16 + (lane & 15)][kb];
#pragma unroll
            for (int i = 0; i < 4; i++)
#pragma unroll
                for (int j = 0; j < 4; j++)
                    acc[i][j] = __builtin_amdgcn_mfma_f32_16x16x32_bf16(af[i], bfr[j], acc[i][j], 0, 0, 0);
        }
    }
    int lr = (lane >> 4) * 4, lc = lane & 15;
#pragma unroll
    for (int i = 0; i < 4; i++)
#pragma unroll
        for (int j = 0; j < 4; j++) {
            int col = n0 + wn + j * 16 + lc;
            int sect = col >> 9, cc = col & 511;
            int row0 = m0 + wm + i * 16 + lr;
            if (sect == 1) {
                // V: transposed store. rows row0..row0+3 -> n consecutive
                int hh = cc >> 6, dd = cc & 63;
                int bb = row0 >> 10, nn = row0 & 1023;
                ushort4 pk;
                pk.x = f2bf(silu(acc[i][j][0]));
                pk.y = f2bf(silu(acc[i][j][1]));
                pk.z = f2bf(silu(acc[i][j][2]));
                pk.w = f2bf(silu(acc[i][j][3]));
                *(ushort4*)&VTg[((size_t)((bb * 8 + hh) * 64 + dd)) * 1024 + nn] = pk;
            } else {
                ushort* dst = (sect == 0) ? Ub : (sect == 2) ? Qb : Kb;
#pragma unroll
                for (int r = 0; r < 4; r++)
                    dst[(size_t)(row0 + r) * 512 + cc] = f2bf(silu(acc[i][j][r]));
            }
        }
}

// ---------------------------------------------------------------------------
// Fused causal attention, barrier-free main loop.
// Grid (16, H, B): 64 M-rows/block, 4 waves x 16 rows. K and VT read directly
// from global (L2-resident); P via wave-private LDS. mt pairwise-remapped for
// load balance among co-resident blocks.
// ---------------------------------------------------------------------------
__global__ __launch_bounds__(256) void attn_kernel(const ushort* __restrict__ Qb,
                                                   const ushort* __restrict__ Kb,
                                                   const ushort* __restrict__ VTg,
                                                   const int* __restrict__ ts,
                                                   const float* __restrict__ pos_w,
                                                   const float* __restrict__ ts_w,
                                                   ushort* __restrict__ Ob) {
    int bx = blockIdx.x;
    int mt = (bx & 1) ? (bx >> 1) : (15 - (bx >> 1));  // balance heavy/light
    int h = blockIdx.y, b = blockIdx.z;
    __shared__ __align__(16) ushort Ps[4][16][72];
    __shared__ float posw[2 * Lc - 1];
    __shared__ float tsw[NBc + 1];
    __shared__ int tss[Lc];
    int tid = threadIdx.x, w = tid >> 6, lane = tid & 63;
    const size_t qkbase = ((size_t)b * Lc) * 512 + h * 64;
    const size_t vtbase = ((size_t)((b * 8 + h) * 64)) * 1024;
    const int m0 = mt * 64;
    for (int i = tid; i < 2 * Lc - 1; i += 256) posw[i] = pos_w[i];
    for (int i = tid; i < Lc; i += 256) tss[i] = ts[b * Lc + i];
    if (tid < NBc + 1) tsw[tid] = ts_w[tid];
    __syncthreads();  // the only barrier

    int lr = (lane >> 4) * 4, lc = lane & 15;
    int kb0 = (lane >> 4) * 8;
    // Q fragments for this wave's 16 rows
    s16x8 qf[2];
#pragma unroll
    for (int ks = 0; ks < 2; ++ks)
        qf[ks] = *(const s16x8*)&Qb[qkbase + (size_t)(m0 + w * 16 + lc) * 512 + ks * 32 + kb0];
    // per-lane m-side timestamps (rows mbase..mbase+3), hoisted out of the loop
    int mbase = m0 + w * 16 + lr;
    int me_r[4];
#pragma unroll
    for (int r = 0; r < 4; r++) {
        int mp = mbase + r + 1;
        me_r[r] = tss[mp < Lc ? mp : (Lc - 1)];
    }
    f32x4 acc_o[4] = {};
    for (int nt = 0; nt <= mt; ++nt) {
        int n0 = nt * 64;
        // S = Q K^T (16 rows x 64 cols), K direct from global (L2)
        f32x4 s[4] = {};
#pragma unroll
        for (int ks = 0; ks < 2; ++ks) {
            int kb = ks * 32 + kb0;
            s16x8 kf[4];
#pragma unroll
            for (int j = 0; j < 4; j++)
                kf[j] = *(const s16x8*)&Kb[qkbase + (size_t)(n0 + j * 16 + lc) * 512 + kb];
#pragma unroll
            for (int j = 0; j < 4; j++)
                s[j] = __builtin_amdgcn_mfma_f32_16x16x32_bf16(qf[ks], kf[j], s[j], 0, 0, 0);
        }
        // bias + silu + mask -> P (wave-private LDS rows)
#pragma unroll
        for (int j = 0; j < 4; j++) {
            int ncol = n0 + j * 16 + lc;
            int tn = tss[ncol];
#pragma unroll
            for (int r = 0; r < 4; r++) {
                int m = mbase + r;
                float val = 0.f;
                if (ncol <= m) {
                    float mag = fmaxf(fabsf((float)(me_r[r] - tn)), 1.f);
                    int bkt = (int)(__log2f(mag) * 2.3028147f);  // ln/0.301
                    bkt = bkt < 0 ? 0 : (bkt > NBc ? NBc : bkt);
                    float sv = s[j][r] + posw[(Lc - 1) + ncol - m] + tsw[bkt];
                    val = silu(sv) * (1.f / (float)Lc);
                }
                Ps[w][lr + r][j * 16 + lc] = f2bf(val);
            }
        }
        // O += P V ; P from own LDS rows (in-wave ordering), V^T direct from global
#pragma unroll
        for (int ks = 0; ks < 2; ++ks) {
            int kb = ks * 32 + kb0;
            s16x8 pa = *(const s16x8*)&Ps[w][lc][kb];
            s16x8 vb[4];
#pragma unroll
            for (int j = 0; j < 4; j++)
                vb[j] = *(const s16x8*)&VTg[vtbase + (size_t)(j * 16 + lc) * 1024 + n0 + kb];
#pragma unroll
            for (int j = 0; j < 4; j++)
                acc_o[j] = __builtin_amdgcn_mfma_f32_16x16x32_bf16(pa, vb[j], acc_o[j], 0, 0, 0);
        }
    }
#pragma unroll
    for (int j = 0; j < 4; j++)
#pragma unroll
        for (int r = 0; r < 4; r++) {
            int m = mbase + r;
            Ob[qkbase + (size_t)m * 512 + j * 16 + lc] = f2bf(acc_o[j][r]);
        }
}

// ---------------------------------------------------------------------------
// LN2(attn) * u -> bf16. One wave per row.
// ---------------------------------------------------------------------------
__global__ __launch_bounds__(256) void ln2_kernel(const ushort* __restrict__ z,
                                                  const ushort* __restrict__ u,
                                                  const float* __restrict__ g,
                                                  const float* __restrict__ bta,
                                                  ushort* __restrict__ outp) {
    int wid = threadIdx.x >> 6, lane = threadIdx.x & 63;
    int row = blockIdx.x * 4 + wid;
    uint4 zv = ((const uint4*)(z + (size_t)row * 512))[lane];
    ushort* zu = (ushort*)&zv;
    float xv[8], s = 0.f, q = 0.f;
#pragma unroll
    for (int i = 0; i < 8; i++) { xv[i] = bf2f(zu[i]); s += xv[i]; q += xv[i] * xv[i]; }
#pragma unroll
    for (int off = 32; off; off >>= 1) { s += __shfl_xor(s, off); q += __shfl_xor(q, off); }
    float mean = s * (1.f / 512.f);
    float var  = q * (1.f / 512.f) - mean * mean;
    float rstd = rsqrtf(var + 1e-6f);
    uint4 uv = ((const uint4*)(u + (size_t)row * 512))[lane];
    ushort* uu = (ushort*)&uv;
    const float4* gv = (const float4*)g; const float4* bv = (const float4*)bta;
    float4 g0 = gv[lane * 2], g1 = gv[lane * 2 + 1];
    float4 b0 = bv[lane * 2], b1 = bv[lane * 2 + 1];
    float G[8] = {g0.x, g0.y, g0.z, g0.w, g1.x, g1.y, g1.z, g1.w};
    float Bv[8] = {b0.x, b0.y, b0.z, b0.w, b1.x, b1.y, b1.z, b1.w};
    union { ushort u16[8]; uint4 v; } pk;
#pragma unroll
    for (int i = 0; i < 8; i++)
        pk.u16[i] = f2bf(((xv[i] - mean) * rstd * G[i] + Bv[i]) * bf2f(uu[i]));
    ((uint4*)(outp + (size_t)row * 512))[lane] = pk.v;
}

// ---------------------------------------------------------------------------
// GEMM2: A2 (8192x512 bf16) @ W2T^T + out_b + x -> fp32
// ---------------------------------------------------------------------------
__global__ __launch_bounds__(256) void gemm2_kernel(const ushort* __restrict__ A,
                                                    const ushort* __restrict__ Bt,
                                                    const float* __restrict__ ob,
                                                    const float* __restrict__ x,
                                                    float* __restrict__ outp) {
    __shared__ __align__(16) ushort As[128][72];
    __shared__ __align__(16) ushort Bs[128][72];
    int tid = threadIdx.x;
    int m0 = blockIdx.x * 128, n0 = blockIdx.y * 128;
    int w = tid >> 6, lane = tid & 63;
    int wm = (w >> 1) * 64, wn = (w & 1) * 64;
    f32x4 acc[4][4] = {};
    for (int k0 = 0; k0 < Dc; k0 += 64) {
        __syncthreads();
#pragma unroll
        for (int c = tid; c < 1024; c += 256) {
            int r = c >> 3, c8 = c & 7;
            *(uint4*)&As[r][c8 * 8] = *(const uint4*)&A[(size_t)(m0 + r) * Dc + k0 + c8 * 8];
            *(uint4*)&Bs[r][c8 * 8] = *(const uint4*)&Bt[(size_t)(n0 + r) * Dc + k0 + c8 * 8];
        }
        __syncthreads();
#pragma unroll
        for (int ks = 0; ks < 2; ++ks) {
            int kb = ks * 32 + (lane >> 4) * 8;
            s16x8 af[4], bfr[4];
#pragma unroll
            for (int i = 0; i < 4; i++) af[i] = *(const s16x8*)&As[wm + i * 16 + (lane & 15)][kb];
#pragma unroll
            for (int j = 0; j < 4; j++) bfr[j] = *(const s16x8*)&Bs[wn + j * 16 + (lane & 15)][kb];
#pragma unroll
            for (int i = 0; i < 4; i++)
#pragma unroll
                for (int j = 0; j < 4; j++)
                    acc[i][j] = __builtin_amdgcn_mfma_f32_16x16x32_bf16(af[i], bfr[j], acc[i][j], 0, 0, 0);
        }
    }
    int lr = (lane >> 4) * 4, lc = lane & 15;
#pragma unroll
    for (int i = 0; i < 4; i++)
#pragma unroll
        for (int j = 0; j < 4; j++) {
            int col = n0 + wn + j * 16 + lc;
            float bias = ob[col];
#pragma unroll
            for (int r = 0; r < 4; r++) {
                int row = m0 + wm + i * 16 + lr + r;
                size_t off = (size_t)row * 512 + col;
                outp[off] = acc[i][j][r] + bias + x[off];
            }
        }
}

// ---------------------------------------------------------------------------
extern "C" void kernel_launch(void* const* d_in, const int* in_sizes, int n_in,
                              void* d_out, int out_size, void* d_ws, size_t ws_size,
                              hipStream_t stream) {
    const float* x      = (const float*)d_in[0];
    const int*   tsp    = (const int*)d_in[1];
    // d_in[2]: attn_mask (implicit causal; unused)
    const float* uvqk_w = (const float*)d_in[3];
    const float* out_w  = (const float*)d_in[4];
    const float* out_b  = (const float*)d_in[5];
    const float* ln1_g  = (const float*)d_in[6];
    const float* ln1_b  = (const float*)d_in[7];
    const float* ln2_g  = (const float*)d_in[8];
    const float* ln2_b  = (const float*)d_in[9];
    const float* ts_w   = (const float*)d_in[10];
    const float* pos_w  = (const float*)d_in[11];
    float* outp = (float*)d_out;

    char* ws = (char*)d_ws;
    size_t off = 0;
    auto alloc = [&](size_t bytes) { char* p = ws + off; off += (bytes + 255) & ~(size_t)255; return p; };
    const size_t MAT = (size_t)ROWS * 512 * sizeof(ushort);  // 8 MB
    ushort* W1T = (ushort*)alloc((size_t)TOTAL_OUT * Dc * 2);  // 2 MB
    ushort* W2T = (ushort*)alloc((size_t)Dc * Dc * 2);         // 0.5 MB
    ushort* X1  = (ushort*)alloc(MAT);
    ushort* Ub  = (ushort*)alloc(MAT);
    ushort* VTg = (ushort*)alloc(MAT);  // V transposed: [(b*8+h)*64+d][n]
    ushort* Qb  = (ushort*)alloc(MAT);
    ushort* Kb  = (ushort*)alloc(MAT);
    ushort* Ob  = (ushort*)alloc(MAT);
    ushort* A2  = X1;  // X1 dead after gemm1 -> reuse for ln2 output

    transpose_cast<<<dim3(TOTAL_OUT / 32, Dc / 32), 256, 0, stream>>>(uvqk_w, W1T, Dc, TOTAL_OUT);
    transpose_cast<<<dim3(Dc / 32, Dc / 32), 256, 0, stream>>>(out_w, W2T, Dc, Dc);
    ln1_kernel<<<ROWS / 4, 256, 0, stream>>>(x, ln1_g, ln1_b, X1);
    gemm1_kernel<<<dim3(ROWS / 128, TOTAL_OUT / 128), 256, 0, stream>>>(X1, W1T, Ub, VTg, Qb, Kb);
    attn_kernel<<<dim3(16, Hc, Bc), 256, 0, stream>>>(Qb, Kb, VTg, tsp, pos_w, ts_w, Ob);
    ln2_kernel<<<ROWS / 4, 256, 0, stream>>>(Ob, Ub, ln2_g, ln2_b, A2);
    gemm2_kernel<<<dim3(ROWS / 128, Dc / 128), 256, 0, stream>>>(A2, W2T, out_b, x, outp);
}

// Round 7
// 259.162 us; speedup vs baseline: 1.0964x; 1.0964x over previous
//
#include <hip/hip_runtime.h>
#include <math.h>

// Problem constants
constexpr int Bc = 8;
constexpr int Lc = 1024;
constexpr int Dc = 512;        // model dim
constexpr int Hc = 8;
constexpr int DHc = 64;
constexpr int DLc = 64;
constexpr int NBc = 128;
constexpr int TOTAL_OUT = 2 * DLc * Hc + 2 * DHc * Hc;  // 2048
constexpr int ROWS = Bc * Lc;  // 8192

using f32x4 = __attribute__((ext_vector_type(4))) float;
using s16x8 = __attribute__((ext_vector_type(8))) short;

__device__ __forceinline__ float bf2f(ushort u) {
    union { unsigned int i; float f; } v; v.i = ((unsigned int)u) << 16; return v.f;
}
__device__ __forceinline__ ushort f2bf(float f) {
    union { float f; unsigned int i; } v; v.f = f;
    unsigned int r = v.i + 0x7fffu + ((v.i >> 16) & 1u);  // RNE
    return (ushort)(r >> 16);
}
// silu via v_exp + v_rcp (1-instr transcendentals) instead of precise divide
__device__ __forceinline__ float silu(float x) {
    float e = __expf(-x);
    return x * __builtin_amdgcn_rcpf(1.0f + e);
}

// ---------------------------------------------------------------------------
// Transpose + cast fp32 (R x C) -> bf16 (C x R)
// ---------------------------------------------------------------------------
__global__ __launch_bounds__(256) void transpose_cast(const float* __restrict__ in,
                                                      ushort* __restrict__ out,
                                                      int R, int C) {
    __shared__ float tile[32][33];
    int bc = blockIdx.x * 32, br = blockIdx.y * 32;
    int tx = threadIdx.x & 31, ty = threadIdx.x >> 5;  // 32x8
    for (int i = ty; i < 32; i += 8) {
        int r = br + i, c = bc + tx;
        tile[i][tx] = (r < R && c < C) ? in[(size_t)r * C + c] : 0.f;
    }
    __syncthreads();
    for (int i = ty; i < 32; i += 8) {
        int c = bc + i, r = br + tx;
        if (c < C && r < R) out[(size_t)c * R + r] = f2bf(tile[tx][i]);
    }
}

// ---------------------------------------------------------------------------
// LN1: x (ROWS x 512 fp32) -> bf16 normalized. One wave per row.
// ---------------------------------------------------------------------------
__global__ __launch_bounds__(256) void ln1_kernel(const float* __restrict__ x,
                                                  const float* __restrict__ g,
                                                  const float* __restrict__ bta,
                                                  ushort* __restrict__ outp) {
    int wid = threadIdx.x >> 6, lane = threadIdx.x & 63;
    int row = blockIdx.x * 4 + wid;
    const float4* xr = (const float4*)(x + (size_t)row * Dc);
    float4 a = xr[lane * 2], c = xr[lane * 2 + 1];
    float xv[8] = {a.x, a.y, a.z, a.w, c.x, c.y, c.z, c.w};
    float s = 0.f, q = 0.f;
#pragma unroll
    for (int i = 0; i < 8; i++) { s += xv[i]; q += xv[i] * xv[i]; }
#pragma unroll
    for (int off = 32; off; off >>= 1) { s += __shfl_xor(s, off); q += __shfl_xor(q, off); }
    float mean = s * (1.f / 512.f);
    float var  = q * (1.f / 512.f) - mean * mean;
    float rstd = rsqrtf(var + 1e-6f);
    const float4* gv = (const float4*)g; const float4* bv = (const float4*)bta;
    float4 g0 = gv[lane * 2], g1 = gv[lane * 2 + 1];
    float4 b0 = bv[lane * 2], b1 = bv[lane * 2 + 1];
    float G[8] = {g0.x, g0.y, g0.z, g0.w, g1.x, g1.y, g1.z, g1.w};
    float Bv[8] = {b0.x, b0.y, b0.z, b0.w, b1.x, b1.y, b1.z, b1.w};
    union { ushort u16[8]; uint4 v; } pk;
#pragma unroll
    for (int i = 0; i < 8; i++) pk.u16[i] = f2bf((xv[i] - mean) * rstd * G[i] + Bv[i]);
    ((uint4*)(outp + (size_t)row * Dc))[lane] = pk.v;
}

// ---------------------------------------------------------------------------
// GEMM1: X1 (8192x512 bf16) @ W1T^T -> silu -> split-store:
//   u, q, k row-major (8192x512 each); V TRANSPOSED: VT[(b*8+h)*64+d][n] (64 heads)
// ---------------------------------------------------------------------------
__global__ __launch_bounds__(256) void gemm1_kernel(const ushort* __restrict__ A,
                                                    const ushort* __restrict__ Bt,
                                                    ushort* __restrict__ Ub,
                                                    ushort* __restrict__ VTg,
                                                    ushort* __restrict__ Qb,
                                                    ushort* __restrict__ Kb) {
    __shared__ __align__(16) ushort As[128][72];
    __shared__ __align__(16) ushort Bs[128][72];
    int tid = threadIdx.x;
    int m0 = blockIdx.x * 128, n0 = blockIdx.y * 128;
    int w = tid >> 6, lane = tid & 63;
    int wm = (w >> 1) * 64, wn = (w & 1) * 64;
    f32x4 acc[4][4] = {};
    for (int k0 = 0; k0 < Dc; k0 += 64) {
        __syncthreads();
#pragma unroll
        for (int c = tid; c < 1024; c += 256) {
            int r = c >> 3, c8 = c & 7;
            *(uint4*)&As[r][c8 * 8] = *(const uint4*)&A[(size_t)(m0 + r) * Dc + k0 + c8 * 8];
            *(uint4*)&Bs[r][c8 * 8] = *(const uint4*)&Bt[(size_t)(n0 + r) * Dc + k0 + c8 * 8];
        }
        __syncthreads();
#pragma unroll
        for (int ks = 0; ks < 2; ++ks) {
            int kb = ks * 32 + (lane >> 4) * 8;
            s16x8 af[4], bfr[4];
#pragma unroll
            for (int i = 0; i < 4; i++) af[i] = *(const s16x8*)&As[wm + i * 16 + (lane & 15)][kb];
#pragma unroll
            for (int j = 0; j < 4; j++) bfr[j] = *(const s16x8*)&Bs[wn + j * 16 + (lane & 15)][kb];
#pragma unroll
            for (int i = 0; i < 4; i++)
#pragma unroll
                for (int j = 0; j < 4; j++)
                    acc[i][j] = __builtin_amdgcn_mfma_f32_16x16x32_bf16(af[i], bfr[j], acc[i][j], 0, 0, 0);
        }
    }
    int lr = (lane >> 4) * 4, lc = lane & 15;
#pragma unroll
    for (int i = 0; i < 4; i++)
#pragma unroll
        for (int j = 0; j < 4; j++) {
            int col = n0 + wn + j * 16 + lc;
            int sect = col >> 9, cc = col & 511;
            int row0 = m0 + wm + i * 16 + lr;
            if (sect == 1) {
                // V: transposed store. rows row0..row0+3 -> n consecutive
                int hh = cc >> 6, dd = cc & 63;
                int bb = row0 >> 10, nn = row0 & 1023;
                ushort4 pk;
                pk.x = f2bf(silu(acc[i][j][0]));
                pk.y = f2bf(silu(acc[i][j][1]));
                pk.z = f2bf(silu(acc[i][j][2]));
                pk.w = f2bf(silu(acc[i][j][3]));
                *(ushort4*)&VTg[((size_t)((bb * 8 + hh) * 64 + dd)) * 1024 + nn] = pk;
            } else {
                ushort* dst = (sect == 0) ? Ub : (sect == 2) ? Qb : Kb;
#pragma unroll
                for (int r = 0; r < 4; r++)
                    dst[(size_t)(row0 + r) * 512 + cc] = f2bf(silu(acc[i][j][r]));
            }
        }
}

// ---------------------------------------------------------------------------
// Fused causal attention, pipelined.
// Grid (16, H, B): 64 M-rows/block, 4 waves x 16 rows.
// K double-buffered in LDS (reg-staged, XOR-swizzled, async-split: load at top
// of iter, ds_write after PV). V^T prefetched direct from global at iter top.
// One barrier per iteration. Ps per-wave LDS bounce for the P fragment.
// ---------------------------------------------------------------------------
__global__ __launch_bounds__(256, 3) void attn_kernel(const ushort* __restrict__ Qb,
                                                      const ushort* __restrict__ Kb,
                                                      const ushort* __restrict__ VTg,
                                                      const int* __restrict__ ts,
                                                      const float* __restrict__ pos_w,
                                                      const float* __restrict__ ts_w,
                                                      ushort* __restrict__ Ob) {
    int bx = blockIdx.x;
    int mt = (bx & 1) ? (bx >> 1) : (15 - (bx >> 1));  // pairwise balance 0..15
    int h = blockIdx.y, b = blockIdx.z;
    __shared__ __align__(16) ushort Ks[2][64][64];   // 16 KB, XOR-swizzled slots
    __shared__ __align__(16) ushort Ps[4][16][72];   // 9 KB, per-wave P bounce
    __shared__ float posw[2 * Lc - 1];
    __shared__ float tsw[NBc + 1];
    __shared__ int tss[Lc];
    int tid = threadIdx.x, w = tid >> 6, lane = tid & 63;
    const size_t qkbase = ((size_t)b * Lc) * 512 + h * 64;
    const size_t vtbase = ((size_t)((b * 8 + h) * 64)) * 1024;
    const int m0 = mt * 64;
    for (int i = tid; i < 2 * Lc - 1; i += 256) posw[i] = pos_w[i];
    for (int i = tid; i < Lc; i += 256) tss[i] = ts[b * Lc + i];
    if (tid < NBc + 1) tsw[tid] = ts_w[tid];

    int lc = lane & 15, g4 = lane >> 4;
    int lr = g4 * 4;
    // --- K staging geometry: thread t covers 32B of the 8KB tile ---
    int sr = tid >> 2;               // tile row 0..63
    int ss0 = (tid & 3) * 2;         // 16B-slot 0,2,4,6
    const ushort* kgrow = Kb + qkbase + (size_t)sr * 512;
    // swizzled LDS offsets (ushort units): row*64 + ((slot ^ (row&7))*8)
    int dso0 = sr * 64 + (((ss0)     ^ (sr & 7)) * 8);
    int dso1 = sr * 64 + (((ss0 + 1) ^ (sr & 7)) * 8);

    // prologue: stage K(0) into Ks[0]
    {
        uint4 ka = *(const uint4*)(kgrow + ss0 * 8);
        uint4 kb_ = *(const uint4*)(kgrow + (ss0 + 1) * 8);
        *(uint4*)&(&Ks[0][0][0])[dso0] = ka;
        *(uint4*)&(&Ks[0][0][0])[dso1] = kb_;
    }
    __syncthreads();

    // Q fragments for this wave's 16 rows
    s16x8 qf[2];
#pragma unroll
    for (int ks = 0; ks < 2; ++ks)
        qf[ks] = *(const s16x8*)&Qb[qkbase + (size_t)(m0 + w * 16 + lc) * 512 + ks * 32 + g4 * 8];
    int mbase = m0 + w * 16 + lr;
    int me_r[4];
#pragma unroll
    for (int r = 0; r < 4; r++) {
        int mp = mbase + r + 1;
        me_r[r] = tss[mp < Lc ? mp : (Lc - 1)];
    }

    f32x4 acc_o[4] = {};
    int ntiles = mt + 1;
    int cur = 0;
    for (int nt = 0; nt < ntiles; ++nt) {
        int n0 = nt * 64;
        // prefetch V^T fragments for THIS tile (used at bottom -> latency covered)
        s16x8 vb[2][4];
#pragma unroll
        for (int ks = 0; ks < 2; ++ks)
#pragma unroll
            for (int j = 0; j < 4; j++)
                vb[ks][j] = *(const s16x8*)&VTg[vtbase + (size_t)(j * 16 + lc) * 1024 + n0 + ks * 32 + g4 * 8];
        // prefetch K(nt+1) into regs (ds_write after PV)
        bool hasnext = (nt + 1 < ntiles);
        uint4 ka = {}, kb_ = {};
        if (hasnext) {
            const ushort* kgn = kgrow + (size_t)(n0 + 64) * 512;
            ka  = *(const uint4*)(kgn + ss0 * 8);
            kb_ = *(const uint4*)(kgn + (ss0 + 1) * 8);
        }
        // S = Q K^T from swizzled LDS
        const ushort* ksb = &Ks[cur][0][0];
        f32x4 s[4] = {};
#pragma unroll
        for (int ks = 0; ks < 2; ++ks) {
            s16x8 kf[4];
#pragma unroll
            for (int j = 0; j < 4; j++)
                kf[j] = *(const s16x8*)&ksb[(j * 16 + lc) * 64 + (((ks * 4 + g4) ^ (lc & 7)) * 8)];
#pragma unroll
            for (int j = 0; j < 4; j++)
                s[j] = __builtin_amdgcn_mfma_f32_16x16x32_bf16(qf[ks], kf[j], s[j], 0, 0, 0);
        }
        // bias + silu + mask -> P (wave-private LDS rows)
#pragma unroll
        for (int j = 0; j < 4; j++) {
            int ncol = n0 + j * 16 + lc;
            int tn = tss[ncol];
#pragma unroll
            for (int r = 0; r < 4; r++) {
                int m = mbase + r;
                float val = 0.f;
                if (ncol <= m) {
                    float mag = fmaxf(fabsf((float)(me_r[r] - tn)), 1.f);
                    int bkt = (int)(__log2f(mag) * 2.3028147f);  // ln/0.301
                    bkt = bkt < 0 ? 0 : (bkt > NBc ? NBc : bkt);
                    float sv = s[j][r] + posw[(Lc - 1) + ncol - m] + tsw[bkt];
                    val = silu(sv) * (1.f / (float)Lc);
                }
                Ps[w][lr + r][j * 16 + lc] = f2bf(val);
            }
        }
        // O += P V  (P from own LDS rows; vb prefetched at top)
#pragma unroll
        for (int ks = 0; ks < 2; ++ks) {
            s16x8 pa = *(const s16x8*)&Ps[w][lc][ks * 32 + g4 * 8];
#pragma unroll
            for (int j = 0; j < 4; j++)
                acc_o[j] = __builtin_amdgcn_mfma_f32_16x16x32_bf16(pa, vb[ks][j], acc_o[j], 0, 0, 0);
        }
        // stage K(nt+1) into the other buffer (readers of it wait at the barrier)
        if (hasnext) {
            ushort* kd = &Ks[cur ^ 1][0][0];
            *(uint4*)&kd[dso0] = ka;
            *(uint4*)&kd[dso1] = kb_;
        }
        __syncthreads();
        cur ^= 1;
    }
#pragma unroll
    for (int j = 0; j < 4; j++)
#pragma unroll
        for (int r = 0; r < 4; r++) {
            int m = mbase + r;
            Ob[qkbase + (size_t)m * 512 + j * 16 + lc] = f2bf(acc_o[j][r]);
        }
}

// ---------------------------------------------------------------------------
// LN2(attn) * u -> bf16. One wave per row.
// ---------------------------------------------------------------------------
__global__ __launch_bounds__(256) void ln2_kernel(const ushort* __restrict__ z,
                                                  const ushort* __restrict__ u,
                                                  const float* __restrict__ g,
                                                  const float* __restrict__ bta,
                                                  ushort* __restrict__ outp) {
    int wid = threadIdx.x >> 6, lane = threadIdx.x & 63;
    int row = blockIdx.x * 4 + wid;
    uint4 zv = ((const uint4*)(z + (size_t)row * 512))[lane];
    ushort* zu = (ushort*)&zv;
    float xv[8], s = 0.f, q = 0.f;
#pragma unroll
    for (int i = 0; i < 8; i++) { xv[i] = bf2f(zu[i]); s += xv[i]; q += xv[i] * xv[i]; }
#pragma unroll
    for (int off = 32; off; off >>= 1) { s += __shfl_xor(s, off); q += __shfl_xor(q, off); }
    float mean = s * (1.f / 512.f);
    float var  = q * (1.f / 512.f) - mean * mean;
    float rstd = rsqrtf(var + 1e-6f);
    uint4 uv = ((const uint4*)(u + (size_t)row * 512))[lane];
    ushort* uu = (ushort*)&uv;
    const float4* gv = (const float4*)g; const float4* bv = (const float4*)bta;
    float4 g0 = gv[lane * 2], g1 = gv[lane * 2 + 1];
    float4 b0 = bv[lane * 2], b1 = bv[lane * 2 + 1];
    float G[8] = {g0.x, g0.y, g0.z, g0.w, g1.x, g1.y, g1.z, g1.w};
    float Bv[8] = {b0.x, b0.y, b0.z, b0.w, b1.x, b1.y, b1.z, b1.w};
    union { ushort u16[8]; uint4 v; } pk;
#pragma unroll
    for (int i = 0; i < 8; i++)
        pk.u16[i] = f2bf(((xv[i] - mean) * rstd * G[i] + Bv[i]) * bf2f(uu[i]));
    ((uint4*)(outp + (size_t)row * 512))[lane] = pk.v;
}

// ---------------------------------------------------------------------------
// GEMM2: A2 (8192x512 bf16) @ W2T^T + out_b + x -> fp32
// ---------------------------------------------------------------------------
__global__ __launch_bounds__(256) void gemm2_kernel(const ushort* __restrict__ A,
                                                    const ushort* __restrict__ Bt,
                                                    const float* __restrict__ ob,
                                                    const float* __restrict__ x,
                                                    float* __restrict__ outp) {
    __shared__ __align__(16) ushort As[128][72];
    __shared__ __align__(16) ushort Bs[128][72];
    int tid = threadIdx.x;
    int m0 = blockIdx.x * 128, n0 = blockIdx.y * 128;
    int w = tid >> 6, lane = tid & 63;
    int wm = (w >> 1) * 64, wn = (w & 1) * 64;
    f32x4 acc[4][4] = {};
    for (int k0 = 0; k0 < Dc; k0 += 64) {
        __syncthreads();
#pragma unroll
        for (int c = tid; c < 1024; c += 256) {
            int r = c >> 3, c8 = c & 7;
            *(uint4*)&As[r][c8 * 8] = *(const uint4*)&A[(size_t)(m0 + r) * Dc + k0 + c8 * 8];
            *(uint4*)&Bs[r][c8 * 8] = *(const uint4*)&Bt[(size_t)(n0 + r) * Dc + k0 + c8 * 8];
        }
        __syncthreads();
#pragma unroll
        for (int ks = 0; ks < 2; ++ks) {
            int kb = ks * 32 + (lane >> 4) * 8;
            s16x8 af[4], bfr[4];
#pragma unroll
            for (int i = 0; i < 4; i++) af[i] = *(const s16x8*)&As[wm + i * 16 + (lane & 15)][kb];
#pragma unroll
            for (int j = 0; j < 4; j++) bfr[j] = *(const s16x8*)&Bs[wn + j * 16 + (lane & 15)][kb];
#pragma unroll
            for (int i = 0; i < 4; i++)
#pragma unroll
                for (int j = 0; j < 4; j++)
                    acc[i][j] = __builtin_amdgcn_mfma_f32_16x16x32_bf16(af[i], bfr[j], acc[i][j], 0, 0, 0);
        }
    }
    int lr = (lane >> 4) * 4, lc = lane & 15;
#pragma unroll
    for (int i = 0; i < 4; i++)
#pragma unroll
        for (int j = 0; j < 4; j++) {
            int col = n0 + wn + j * 16 + lc;
            float bias = ob[col];
#pragma unroll
            for (int r = 0; r < 4; r++) {
                int row = m0 + wm + i * 16 + lr + r;
                size_t off = (size_t)row * 512 + col;
                outp[off] = acc[i][j][r] + bias + x[off];
            }
        }
}

// ---------------------------------------------------------------------------
extern "C" void kernel_launch(void* const* d_in, const int* in_sizes, int n_in,
                              void* d_out, int out_size, void* d_ws, size_t ws_size,
                              hipStream_t stream) {
    const float* x      = (const float*)d_in[0];
    const int*   tsp    = (const int*)d_in[1];
    // d_in[2]: attn_mask (implicit causal; unused)
    const float* uvqk_w = (const float*)d_in[3];
    const float* out_w  = (const float*)d_in[4];
    const float* out_b  = (const float*)d_in[5];
    const float* ln1_g  = (const float*)d_in[6];
    const float* ln1_b  = (const float*)d_in[7];
    const float* ln2_g  = (const float*)d_in[8];
    const float* ln2_b  = (const float*)d_in[9];
    const float* ts_w   = (const float*)d_in[10];
    const float* pos_w  = (const float*)d_in[11];
    float* outp = (float*)d_out;

    char* ws = (char*)d_ws;
    size_t off = 0;
    auto alloc = [&](size_t bytes) { char* p = ws + off; off += (bytes + 255) & ~(size_t)255; return p; };
    const size_t MAT = (size_t)ROWS * 512 * sizeof(ushort);  // 8 MB
    ushort* W1T = (ushort*)alloc((size_t)TOTAL_OUT * Dc * 2);  // 2 MB
    ushort* W2T = (ushort*)alloc((size_t)Dc * Dc * 2);         // 0.5 MB
    ushort* X1  = (ushort*)alloc(MAT);
    ushort* Ub  = (ushort*)alloc(MAT);
    ushort* VTg = (ushort*)alloc(MAT);  // V transposed: [(b*8+h)*64+d][n]
    ushort* Qb  = (ushort*)alloc(MAT);
    ushort* Kb  = (ushort*)alloc(MAT);
    ushort* Ob  = (ushort*)alloc(MAT);
    ushort* A2  = X1;  // X1 dead after gemm1 -> reuse for ln2 output

    transpose_cast<<<dim3(TOTAL_OUT / 32, Dc / 32), 256, 0, stream>>>(uvqk_w, W1T, Dc, TOTAL_OUT);
    transpose_cast<<<dim3(Dc / 32, Dc / 32), 256, 0, stream>>>(out_w, W2T, Dc, Dc);
    ln1_kernel<<<ROWS / 4, 256, 0, stream>>>(x, ln1_g, ln1_b, X1);
    gemm1_kernel<<<dim3(ROWS / 128, TOTAL_OUT / 128), 256, 0, stream>>>(X1, W1T, Ub, VTg, Qb, Kb);
    attn_kernel<<<dim3(16, Hc, Bc), 256, 0, stream>>>(Qb, Kb, VTg, tsp, pos_w, ts_w, Ob);
    ln2_kernel<<<ROWS / 4, 256, 0, stream>>>(Ob, Ub, ln2_g, ln2_b, A2);
    gemm2_kernel<<<dim3(ROWS / 128, Dc / 128), 256, 0, stream>>>(A2, W2T, out_b, x, outp);
}